// Round 18
// baseline (26.860 us; speedup 1.0000x reference)
//
#include <hip/hip_runtime.h>

#define NQ 5
#define NL 6
#define NG 4
#define DIM 32
#define PATCH 16
#define CHUNKS 4

typedef _Float16 half8 __attribute__((ext_vector_type(8)));
typedef float f32x4 __attribute__((ext_vector_type(4)));

// CZ-chain sign: flip amplitude i iff # adjacent set-bit pairs is odd.
__device__ __forceinline__ int flip_par(int i) {
    int p = i & (i >> 1) & 0xF;
    p ^= p >> 2; p ^= p >> 1;
    return p & 1;
}

// R18 = R17 with CHUNKS 2 -> 4 (256 blocks x 1024 batches; 1 block/CU).
// Same validated pipeline: chunk-(c+1) prologue (x-load/trig/base/relay/
// B-frags) issues after chunk-c's drain stores -> hides under the drain.
// Sim + A-frag build amortize over 1024 batches. All register-array
// indices compile-time (rule #20). Main loop/staging/drain byte-identical
// to the R14/R16/R17 passes.
__global__ __launch_bounds__(256, 4) void qgen16(
        const float* __restrict__ x, const float* __restrict__ qp,
        float* __restrict__ out) {
    __shared__ __align__(16) f32x4 smem[4][512];   // 32 KB relay/stage
    __shared__ float lmMs[64 * DIM];               // 8 KB dedicated M

    const int t = threadIdx.x;
    const int wid = t >> 6, lane = t & 63;
    const int l15 = lane & 15, kg = lane >> 4;
    const bool bwave = (wid == (blockIdx.x & 3));  // spread sim wave
    const float RV = 0.07957747154594767f; // 0.5/(2*pi): v_sin/v_cos take revolutions

    f32x4* relay = smem[wid];
    f32x4* stage = smem[wid];

    float base[DIM];
    half8 BhF[4], BlF[4];

    // x -> trig -> product state for chunk c
    // (batch = blk*(256*CHUNKS) + c*256 + wid*64 + lane)
    auto load_base = [&](int c) {
        const float* xp = x + ((size_t)blockIdx.x * (256 * CHUNKS) + c * 256
                               + wid * 64 + lane) * NQ;
        float cn[NQ], sn[NQ];
        #pragma unroll
        for (int w = 0; w < NQ; ++w) {
            float h = xp[w] * RV;
            cn[w] = __builtin_amdgcn_cosf(h);
            sn[w] = __builtin_amdgcn_sinf(h);
        }
        base[0] = cn[0]; base[1] = sn[0];
        #pragma unroll
        for (int w = 1; w < NQ; ++w) {
            #pragma unroll
            for (int j = (1 << w) - 1; j >= 0; --j) {
                float v = base[j];
                base[2*j + 1] = v * sn[w];
                base[2*j]     = v * cn[w];
            }
        }
    };

    // relay base -> B-frag order (wave-private slab; same-wave in-order DS)
    auto build_bfrags = [&]() {
        #pragma unroll
        for (int q = 0; q < 8; ++q)
            relay[q * 64 + lane] = *(f32x4*)&base[q * 4];
        #pragma unroll
        for (int tb = 0; tb < 4; ++tb) {
            f32x4 r0 = relay[(kg*2 + 0) * 64 + tb*16 + l15];
            f32x4 r1 = relay[(kg*2 + 1) * 64 + tb*16 + l15];
            float b8[8] = {r0[0], r0[1], r0[2], r0[3], r1[0], r1[1], r1[2], r1[3]};
            half8 h, lo;
            #pragma unroll
            for (int e = 0; e < 8; ++e) {
                _Float16 hh = (_Float16)b8[e];
                h[e]  = hh;
                lo[e] = (_Float16)(b8[e] - (float)hh);
            }
            BhF[tb] = h; BlF[tb] = lo;
        }
    };

    if (!bwave) {
        load_base(0);
        build_bfrags();          // non-B waves progress while the sim runs
    } else {
        // ADJOINT basis sim -> M rows (math verified R12-R17):
        // row r of M = U'^T e_r; loop l=5..0 apply RY(-theta), sign after
        // each layer except l=0. lane -> (g=lane>>4, r=lane&15).
        const int g = lane >> 4;
        const int r = lane & 15;
        float st[DIM];
        #pragma unroll
        for (int i = 0; i < DIM; ++i) st[i] = (i == r) ? 1.0f : 0.0f;
        #pragma unroll
        for (int l = NL - 1; l >= 0; --l) {
            #pragma unroll
            for (int w = 0; w < NQ; ++w) {
                float h = qp[g*(NL*NQ) + l*NQ + w] * RV;
                float c = __builtin_amdgcn_cosf(h);
                float s = __builtin_amdgcn_sinf(h);
                const int bit = 4 - w, str = 1 << bit;
                #pragma unroll
                for (int p = 0; p < 16; ++p) {
                    int lo = ((p >> bit) << (bit + 1)) | (p & (str - 1));
                    int hi = lo + str;
                    float a0 = st[lo], a1 = st[hi];
                    st[lo] = c*a0 + s*a1;      // RY(-theta): transpose of fwd
                    st[hi] = c*a1 - s*a0;
                }
            }
            if (l != 0) {
                #pragma unroll
                for (int i = 0; i < DIM; ++i)
                    if (flip_par(i)) st[i] = -st[i];
            }
        }
        // swizzled write: bank (i+lane)&31 over 64 lanes = 2-way (free)
        #pragma unroll
        for (int i = 0; i < DIM; ++i)
            lmMs[(lane << 5) + ((i + lane) & 31)] = st[i];
    }
    __syncthreads();   // lmMs ready; the only barrier in the kernel

    // ---- A-fragments from lmMs, ONCE per block (b32 reads, 2-way max)
    half8 MhA[NG], MlA[NG];
    #pragma unroll
    for (int g = 0; g < NG; ++g) {
        const int row = g * PATCH + l15;
        float m8[8];
        #pragma unroll
        for (int e = 0; e < 8; ++e)
            m8[e] = lmMs[(row << 5) + ((kg*8 + e + row) & 31)];
        half8 h, lo;
        #pragma unroll
        for (int e = 0; e < 8; ++e) {
            _Float16 hh = (_Float16)m8[e];
            h[e]  = hh;
            lo[e] = (_Float16)(m8[e] - (float)hh);
        }
        MhA[g] = h; MlA[g] = lo;
    }

    if (bwave) { load_base(0); build_bfrags(); }   // B-wave catches up

    // ---- chunk loop, FULLY UNROLLED (all register indices compile-time).
    // Per chunk: 4 tb x 4 g x 3 MFMA -> swizzled stage -> 4x1KB contiguous
    // stores; then next chunk's prologue issues (hides under store drain).
    #pragma unroll
    for (int c = 0; c < CHUNKS; ++c) {
        f32x4* ob4 = (f32x4*)(out +
            ((size_t)blockIdx.x * (256 * CHUNKS) + c * 256 + wid * 64) * 64);
        #pragma unroll
        for (int tb = 0; tb < 4; ++tb) {
            #pragma unroll
            for (int g = 0; g < NG; ++g) {
                f32x4 acc = {0.f, 0.f, 0.f, 0.f};
                acc = __builtin_amdgcn_mfma_f32_16x16x32_f16(MhA[g], BhF[tb], acc, 0, 0, 0);
                acc = __builtin_amdgcn_mfma_f32_16x16x32_f16(MlA[g], BhF[tb], acc, 0, 0, 0);
                acc = __builtin_amdgcn_mfma_f32_16x16x32_f16(MhA[g], BlF[tb], acc, 0, 0, 0);
                // D layout (m89-verified): reg r = slot kg*4+r, col l15 = batch.
                float p0 = acc[0]*acc[0], p1 = acc[1]*acc[1];
                float p2 = acc[2]*acc[2], p3 = acc[3]*acc[3];
                float mx = fmaxf(fmaxf(p0, p1), fmaxf(p2, p3));
                mx = fmaxf(mx, __shfl_xor(mx, 16, 64));   // combine the 4 kg lanes
                mx = fmaxf(mx, __shfl_xor(mx, 32, 64));
                float inv = __builtin_amdgcn_rcpf(mx);
                // swizzled slab: [batch l15][f4-slot (g*4+kg) ^ l15]
                f32x4 v = {p0*inv, p1*inv, p2*inv, p3*inv};
                stage[l15 * 16 + ((g*4 + kg) ^ l15)] = v;
            }
            // drain: 4 KB contiguous (full 256-B rows); same-wave in-order DS
            #pragma unroll
            for (int j = 0; j < 4; ++j) {
                int f  = lane + 64 * j;      // f4 index within the tb region
                int br = f >> 4;             // local batch 0..15
                int sl = f & 15;             // f4 slot within the row
                ob4[tb * 256 + f] = stage[br * 16 + (sl ^ br)];
            }
        }
        if (c + 1 < CHUNKS) {
            load_base(c + 1);    // issues while chunk-c stores drain
            build_bfrags();
        }
    }
}

extern "C" void kernel_launch(void* const* d_in, const int* in_sizes, int n_in,
                              void* d_out, int out_size, void* d_ws, size_t ws_size,
                              hipStream_t stream) {
    const float* x  = (const float*)d_in[0];
    const float* qp = (const float*)d_in[1];
    float* out = (float*)d_out;
    const int B = in_sizes[0] / NQ;          // 262144
    qgen16<<<B / (256 * CHUNKS), 256, 0, stream>>>(x, qp, out);
}

// Round 19
// 22.368 us; speedup vs baseline: 1.2008x; 1.2008x over previous
//
#include <hip/hip_runtime.h>

#define NQ 5
#define NL 6
#define NG 4
#define DIM 32
#define PATCH 16
#define CHUNKS 2

typedef _Float16 half8 __attribute__((ext_vector_type(8)));
typedef float f32x4 __attribute__((ext_vector_type(4)));

// CZ-chain sign: flip amplitude i iff # adjacent set-bit pairs is odd.
__device__ __forceinline__ int flip_par(int i) {
    int p = i & (i >> 1) & 0xF;
    p ^= p >> 2; p ^= p >> 1;
    return p & 1;
}

// R19 = R17 (22.5 µs, best) with the serial 1-wave sim replaced by a
// DISTRIBUTED sim: wave wid simulates generator g=wid's 16 rows, 4 lanes
// per row (8 elements each). Gates on bits 0-2 intra-lane, bits 3-4 via
// shfl_xor(1/2) in the 4-lane group; CZ signs = 8 precomputed +-1 lane
// multipliers; c,s wave-uniform. Same per-element arithmetic order ->
// bitwise-identical M. All waves do equal work -> balanced barrier, no
// bwave catch-up. Chunk-0 x-loads issue BEFORE the sim (latency hides).
// Chunk pipeline / staging / drain byte-identical to R17.
__global__ __launch_bounds__(256, 4) void qgen17(
        const float* __restrict__ x, const float* __restrict__ qp,
        float* __restrict__ out) {
    __shared__ __align__(16) f32x4 smem[4][512];   // 32 KB relay/stage
    __shared__ float lmMs[64 * DIM];               // 8 KB dedicated M

    const int t = threadIdx.x;
    const int wid = t >> 6, lane = t & 63;
    const int l15 = lane & 15, kg = lane >> 4;
    const float RV = 0.07957747154594767f; // 0.5/(2*pi): v_sin/v_cos take revolutions

    f32x4* relay = smem[wid];
    f32x4* stage = smem[wid];

    float base[DIM];
    half8 BhF[4], BlF[4];

    // ---- x loads for chunk c -> registers (issue early; latency hides)
    float xv[NQ];
    auto load_x = [&](int c) {
        const float* xp = x + ((size_t)blockIdx.x * (256 * CHUNKS) + c * 256
                               + wid * 64 + lane) * NQ;
        #pragma unroll
        for (int w = 0; w < NQ; ++w) xv[w] = xp[w];
    };
    // trig + product state from xv (verified R1-R17)
    auto build_base = [&]() {
        float cn[NQ], sn[NQ];
        #pragma unroll
        for (int w = 0; w < NQ; ++w) {
            float h = xv[w] * RV;
            cn[w] = __builtin_amdgcn_cosf(h);
            sn[w] = __builtin_amdgcn_sinf(h);
        }
        base[0] = cn[0]; base[1] = sn[0];
        #pragma unroll
        for (int w = 1; w < NQ; ++w) {
            #pragma unroll
            for (int j = (1 << w) - 1; j >= 0; --j) {
                float v = base[j];
                base[2*j + 1] = v * sn[w];
                base[2*j]     = v * cn[w];
            }
        }
    };
    // relay base -> B-frag order (wave-private slab; same-wave in-order DS)
    auto build_bfrags = [&]() {
        #pragma unroll
        for (int q = 0; q < 8; ++q)
            relay[q * 64 + lane] = *(f32x4*)&base[q * 4];
        #pragma unroll
        for (int tb = 0; tb < 4; ++tb) {
            f32x4 r0 = relay[(kg*2 + 0) * 64 + tb*16 + l15];
            f32x4 r1 = relay[(kg*2 + 1) * 64 + tb*16 + l15];
            float b8[8] = {r0[0], r0[1], r0[2], r0[3], r1[0], r1[1], r1[2], r1[3]};
            half8 h, lo;
            #pragma unroll
            for (int e = 0; e < 8; ++e) {
                _Float16 hh = (_Float16)b8[e];
                h[e]  = hh;
                lo[e] = (_Float16)(b8[e] - (float)hh);
            }
            BhF[tb] = h; BlF[tb] = lo;
        }
    };

    load_x(0);   // chunk-0 x in flight during the sim

    // ---- distributed ADJOINT sim: g = wid, row rl = lane>>2, sub = lane&3,
    // elements i = sub*8+e. Math verified R12-R18 (same op order per element).
    {
        const int g  = wid;
        const int rl = lane >> 2, sub = lane & 3;
        float st[8], sgn[8];
        #pragma unroll
        for (int e = 0; e < 8; ++e) {
            st[e]  = (sub*8 + e == rl) ? 1.0f : 0.0f;
            sgn[e] = flip_par(sub*8 + e) ? -1.0f : 1.0f;
        }
        #pragma unroll
        for (int l = NL - 1; l >= 0; --l) {
            #pragma unroll
            for (int w = 0; w < NQ; ++w) {
                float h = qp[g*(NL*NQ) + l*NQ + w] * RV;
                float c = __builtin_amdgcn_cosf(h);
                float s = __builtin_amdgcn_sinf(h);
                if (w == 0) {            // str16: bit4 = sub>>1, partner lane^2
                    float ss = (sub & 2) ? -s : s;
                    #pragma unroll
                    for (int e = 0; e < 8; ++e) {
                        float p = __shfl_xor(st[e], 2, 64);
                        st[e] = c*st[e] + ss*p;
                    }
                } else if (w == 1) {     // str8: bit3 = sub&1, partner lane^1
                    float ss = (sub & 1) ? -s : s;
                    #pragma unroll
                    for (int e = 0; e < 8; ++e) {
                        float p = __shfl_xor(st[e], 1, 64);
                        st[e] = c*st[e] + ss*p;
                    }
                } else {                 // intra-lane: str = 1<<(4-w) in {4,2,1}
                    const int str = 1 << (4 - w);
                    #pragma unroll
                    for (int e = 0; e < 8; ++e) {
                        if (!(e & str)) {
                            float a0 = st[e], a1 = st[e + str];
                            st[e]       = c*a0 + s*a1;   // adjoint RY
                            st[e + str] = c*a1 - s*a0;
                        }
                    }
                }
            }
            if (l != 0) {
                #pragma unroll
                for (int e = 0; e < 8; ++e) st[e] *= sgn[e];
            }
        }
        // write 8 elements, swizzle (i+row)&31 (matches A-frag read): banks
        // (row + sub*8 + e)&31 over 64 lanes = exact 2-way (free).
        const int row = g * PATCH + rl;
        #pragma unroll
        for (int e = 0; e < 8; ++e)
            lmMs[(row << 5) + ((sub*8 + e + row) & 31)] = st[e];
    }

    build_base();     // chunk-0 trig/base (xv arrived during sim)
    build_bfrags();
    __syncthreads();  // lmMs ready; balanced arrival (all waves equal work)

    // ---- A-fragments from lmMs (b32 reads, 2-way max), f16 hi/lo split
    half8 MhA[NG], MlA[NG];
    #pragma unroll
    for (int g = 0; g < NG; ++g) {
        const int row = g * PATCH + l15;
        float m8[8];
        #pragma unroll
        for (int e = 0; e < 8; ++e)
            m8[e] = lmMs[(row << 5) + ((kg*8 + e + row) & 31)];
        half8 h, lo;
        #pragma unroll
        for (int e = 0; e < 8; ++e) {
            _Float16 hh = (_Float16)m8[e];
            h[e]  = hh;
            lo[e] = (_Float16)(m8[e] - (float)hh);
        }
        MhA[g] = h; MlA[g] = lo;
    }

    // ---- chunk loop, FULLY UNROLLED (rule #20: all reg indices static).
    // Per chunk: 4 tb x 4 g x 3 MFMA -> swizzled stage -> 4x1KB contiguous
    // stores; next chunk's prologue issues under the store drain. (R17)
    #pragma unroll
    for (int c = 0; c < CHUNKS; ++c) {
        f32x4* ob4 = (f32x4*)(out +
            ((size_t)blockIdx.x * (256 * CHUNKS) + c * 256 + wid * 64) * 64);
        #pragma unroll
        for (int tb = 0; tb < 4; ++tb) {
            #pragma unroll
            for (int g = 0; g < NG; ++g) {
                f32x4 acc = {0.f, 0.f, 0.f, 0.f};
                acc = __builtin_amdgcn_mfma_f32_16x16x32_f16(MhA[g], BhF[tb], acc, 0, 0, 0);
                acc = __builtin_amdgcn_mfma_f32_16x16x32_f16(MlA[g], BhF[tb], acc, 0, 0, 0);
                acc = __builtin_amdgcn_mfma_f32_16x16x32_f16(MhA[g], BlF[tb], acc, 0, 0, 0);
                // D layout (m89-verified): reg r = slot kg*4+r, col l15 = batch.
                float p0 = acc[0]*acc[0], p1 = acc[1]*acc[1];
                float p2 = acc[2]*acc[2], p3 = acc[3]*acc[3];
                float mx = fmaxf(fmaxf(p0, p1), fmaxf(p2, p3));
                mx = fmaxf(mx, __shfl_xor(mx, 16, 64));   // combine the 4 kg lanes
                mx = fmaxf(mx, __shfl_xor(mx, 32, 64));
                float inv = __builtin_amdgcn_rcpf(mx);
                // swizzled slab: [batch l15][f4-slot (g*4+kg) ^ l15]
                f32x4 v = {p0*inv, p1*inv, p2*inv, p3*inv};
                stage[l15 * 16 + ((g*4 + kg) ^ l15)] = v;
            }
            // drain: 4 KB contiguous (full 256-B rows); same-wave in-order DS
            #pragma unroll
            for (int j = 0; j < 4; ++j) {
                int f  = lane + 64 * j;      // f4 index within the tb region
                int br = f >> 4;             // local batch 0..15
                int sl = f & 15;             // f4 slot within the row
                ob4[tb * 256 + f] = stage[br * 16 + (sl ^ br)];
            }
        }
        if (c + 1 < CHUNKS) {
            load_x(c + 1);       // issues while chunk-c stores drain
            build_base();
            build_bfrags();
        }
    }
}

extern "C" void kernel_launch(void* const* d_in, const int* in_sizes, int n_in,
                              void* d_out, int out_size, void* d_ws, size_t ws_size,
                              hipStream_t stream) {
    const float* x  = (const float*)d_in[0];
    const float* qp = (const float*)d_in[1];
    float* out = (float*)d_out;
    const int B = in_sizes[0] / NQ;          // 262144
    qgen17<<<B / (256 * CHUNKS), 256, 0, stream>>>(x, qp, out);
}

// Round 20
// 21.373 us; speedup vs baseline: 1.2567x; 1.0466x over previous
//
#include <hip/hip_runtime.h>

#define NQ 5
#define NL 6
#define NG 4
#define DIM 32
#define PATCH 16
#define CHUNKS 2

typedef _Float16 half8 __attribute__((ext_vector_type(8)));
typedef float f32x4 __attribute__((ext_vector_type(4)));

// CZ-chain sign: flip amplitude i iff # adjacent set-bit pairs is odd.
__device__ __forceinline__ int flip_par(int i) {
    int p = i & (i >> 1) & 0xF;
    p ^= p >> 2; p ^= p >> 1;
    return p & 1;
}

// R20 = R19 (22.4 µs) with the stage+drain LDS round-trip DELETED.
// With tb-outer/g-inner, each lane's 4 direct dwordx4 stores (g=0..3) land
// in one 256-B batch row within a ~100-cyc window -> merge to 2 full 128-B
// lines in L2 before writeback (same 65.5 MB ideal WRITE as R9 measured).
// Removes 128 b128 DS ops per lane per chunk (the serialized write->read
// transpose chain) and ~4x of the CU LDS-pipe pressure.
// Everything else identical to R19: distributed sim, relay/B-frags,
// CHUNKS=2 prologue-under-drain pipeline (R17-validated).
__global__ __launch_bounds__(256, 4) void qgen18(
        const float* __restrict__ x, const float* __restrict__ qp,
        float* __restrict__ out) {
    __shared__ __align__(16) f32x4 smem[4][512];   // 32 KB relay slabs
    __shared__ float lmMs[64 * DIM];               // 8 KB dedicated M

    const int t = threadIdx.x;
    const int wid = t >> 6, lane = t & 63;
    const int l15 = lane & 15, kg = lane >> 4;
    const float RV = 0.07957747154594767f; // 0.5/(2*pi): v_sin/v_cos take revolutions

    f32x4* relay = smem[wid];

    float base[DIM];
    half8 BhF[4], BlF[4];

    // ---- x loads for chunk c -> registers (issue early; latency hides)
    float xv[NQ];
    auto load_x = [&](int c) {
        const float* xp = x + ((size_t)blockIdx.x * (256 * CHUNKS) + c * 256
                               + wid * 64 + lane) * NQ;
        #pragma unroll
        for (int w = 0; w < NQ; ++w) xv[w] = xp[w];
    };
    // trig + product state from xv (verified R1-R19)
    auto build_base = [&]() {
        float cn[NQ], sn[NQ];
        #pragma unroll
        for (int w = 0; w < NQ; ++w) {
            float h = xv[w] * RV;
            cn[w] = __builtin_amdgcn_cosf(h);
            sn[w] = __builtin_amdgcn_sinf(h);
        }
        base[0] = cn[0]; base[1] = sn[0];
        #pragma unroll
        for (int w = 1; w < NQ; ++w) {
            #pragma unroll
            for (int j = (1 << w) - 1; j >= 0; --j) {
                float v = base[j];
                base[2*j + 1] = v * sn[w];
                base[2*j]     = v * cn[w];
            }
        }
    };
    // relay base -> B-frag order (wave-private slab; same-wave in-order DS)
    auto build_bfrags = [&]() {
        #pragma unroll
        for (int q = 0; q < 8; ++q)
            relay[q * 64 + lane] = *(f32x4*)&base[q * 4];
        #pragma unroll
        for (int tb = 0; tb < 4; ++tb) {
            f32x4 r0 = relay[(kg*2 + 0) * 64 + tb*16 + l15];
            f32x4 r1 = relay[(kg*2 + 1) * 64 + tb*16 + l15];
            float b8[8] = {r0[0], r0[1], r0[2], r0[3], r1[0], r1[1], r1[2], r1[3]};
            half8 h, lo;
            #pragma unroll
            for (int e = 0; e < 8; ++e) {
                _Float16 hh = (_Float16)b8[e];
                h[e]  = hh;
                lo[e] = (_Float16)(b8[e] - (float)hh);
            }
            BhF[tb] = h; BlF[tb] = lo;
        }
    };

    load_x(0);   // chunk-0 x in flight during the sim

    // ---- distributed ADJOINT sim (verified R19): g = wid, row rl = lane>>2,
    // sub = lane&3, elements i = sub*8+e. Bitwise-identical M.
    {
        const int g  = wid;
        const int rl = lane >> 2, sub = lane & 3;
        float st[8], sgn[8];
        #pragma unroll
        for (int e = 0; e < 8; ++e) {
            st[e]  = (sub*8 + e == rl) ? 1.0f : 0.0f;
            sgn[e] = flip_par(sub*8 + e) ? -1.0f : 1.0f;
        }
        #pragma unroll
        for (int l = NL - 1; l >= 0; --l) {
            #pragma unroll
            for (int w = 0; w < NQ; ++w) {
                float h = qp[g*(NL*NQ) + l*NQ + w] * RV;
                float c = __builtin_amdgcn_cosf(h);
                float s = __builtin_amdgcn_sinf(h);
                if (w == 0) {            // bit4 = sub>>1, partner lane^2
                    float ss = (sub & 2) ? -s : s;
                    #pragma unroll
                    for (int e = 0; e < 8; ++e) {
                        float p = __shfl_xor(st[e], 2, 64);
                        st[e] = c*st[e] + ss*p;
                    }
                } else if (w == 1) {     // bit3 = sub&1, partner lane^1
                    float ss = (sub & 1) ? -s : s;
                    #pragma unroll
                    for (int e = 0; e < 8; ++e) {
                        float p = __shfl_xor(st[e], 1, 64);
                        st[e] = c*st[e] + ss*p;
                    }
                } else {                 // intra-lane: str = 1<<(4-w) in {4,2,1}
                    const int str = 1 << (4 - w);
                    #pragma unroll
                    for (int e = 0; e < 8; ++e) {
                        if (!(e & str)) {
                            float a0 = st[e], a1 = st[e + str];
                            st[e]       = c*a0 + s*a1;   // adjoint RY
                            st[e + str] = c*a1 - s*a0;
                        }
                    }
                }
            }
            if (l != 0) {
                #pragma unroll
                for (int e = 0; e < 8; ++e) st[e] *= sgn[e];
            }
        }
        const int row = g * PATCH + rl;
        #pragma unroll
        for (int e = 0; e < 8; ++e)
            lmMs[(row << 5) + ((sub*8 + e + row) & 31)] = st[e];
    }

    build_base();     // chunk-0 trig/base (xv arrived during sim)
    build_bfrags();
    __syncthreads();  // lmMs ready; balanced arrival (all waves equal work)

    // ---- A-fragments from lmMs (b32 reads, 2-way max), f16 hi/lo split
    half8 MhA[NG], MlA[NG];
    #pragma unroll
    for (int g = 0; g < NG; ++g) {
        const int row = g * PATCH + l15;
        float m8[8];
        #pragma unroll
        for (int e = 0; e < 8; ++e)
            m8[e] = lmMs[(row << 5) + ((kg*8 + e + row) & 31)];
        half8 h, lo;
        #pragma unroll
        for (int e = 0; e < 8; ++e) {
            _Float16 hh = (_Float16)m8[e];
            h[e]  = hh;
            lo[e] = (_Float16)(m8[e] - (float)hh);
        }
        MhA[g] = h; MlA[g] = lo;
    }

    // ---- chunk loop, FULLY UNROLLED (rule #20). Per tb: 4 g x 3 MFMA ->
    // DIRECT dwordx4 stores (4 per lane, one 256-B row, back-to-back ->
    // L2 merges to full lines). Next chunk's prologue under the drain.
    #pragma unroll
    for (int c = 0; c < CHUNKS; ++c) {
        float* ob = out + ((size_t)blockIdx.x * (256 * CHUNKS) + c * 256
                           + wid * 64) * 64;
        #pragma unroll
        for (int tb = 0; tb < 4; ++tb) {
            #pragma unroll
            for (int g = 0; g < NG; ++g) {
                f32x4 acc = {0.f, 0.f, 0.f, 0.f};
                acc = __builtin_amdgcn_mfma_f32_16x16x32_f16(MhA[g], BhF[tb], acc, 0, 0, 0);
                acc = __builtin_amdgcn_mfma_f32_16x16x32_f16(MlA[g], BhF[tb], acc, 0, 0, 0);
                acc = __builtin_amdgcn_mfma_f32_16x16x32_f16(MhA[g], BlF[tb], acc, 0, 0, 0);
                // D layout (m89-verified): reg r = slot kg*4+r, col l15 = batch.
                float p0 = acc[0]*acc[0], p1 = acc[1]*acc[1];
                float p2 = acc[2]*acc[2], p3 = acc[3]*acc[3];
                float mx = fmaxf(fmaxf(p0, p1), fmaxf(p2, p3));
                mx = fmaxf(mx, __shfl_xor(mx, 16, 64));   // combine the 4 kg lanes
                mx = fmaxf(mx, __shfl_xor(mx, 32, 64));
                float inv = __builtin_amdgcn_rcpf(mx);
                f32x4 v = {p0*inv, p1*inv, p2*inv, p3*inv};
                // direct: batch (tb*16+l15) row, slot quad g*16+kg*4
                *(f32x4*)&ob[(tb*16 + l15)*64 + g*16 + kg*4] = v;
            }
        }
        if (c + 1 < CHUNKS) {
            load_x(c + 1);       // issues while chunk-c stores drain
            build_base();
            build_bfrags();
        }
    }
}

extern "C" void kernel_launch(void* const* d_in, const int* in_sizes, int n_in,
                              void* d_out, int out_size, void* d_ws, size_t ws_size,
                              hipStream_t stream) {
    const float* x  = (const float*)d_in[0];
    const float* qp = (const float*)d_in[1];
    float* out = (float*)d_out;
    const int B = in_sizes[0] / NQ;          // 262144
    qgen18<<<B / (256 * CHUNKS), 256, 0, stream>>>(x, qp, out);
}

// Round 21
// 21.124 us; speedup vs baseline: 1.2715x; 1.0118x over previous
//
#include <hip/hip_runtime.h>

#define NQ 5
#define NL 6
#define NG 4
#define DIM 32
#define PATCH 16
#define CHUNKS 1

typedef _Float16 half8 __attribute__((ext_vector_type(8)));
typedef float f32x4 __attribute__((ext_vector_type(4)));

// CZ-chain sign: flip amplitude i iff # adjacent set-bit pairs is odd.
__device__ __forceinline__ int flip_par(int i) {
    int p = i & (i >> 1) & 0xF;
    p ^= p >> 2; p ^= p >> 1;
    return p & 1;
}

// R21 = R20 (21.4 µs) with ONE variable: CHUNKS 2 -> 1, grid 512 -> 1024
// (4 blocks/CU instead of 2). Tests the per-CU outstanding-store-credit
// hypothesis: 16 waves/CU during the store burst vs 8. Trades away the
// intra-block chunk pipeline (R17's -2 µs under the OLD staged structure)
// for 2x store sources under the NEW lean structure (direct stores,
// distributed sim, x-prefetch) -- the untested cell of the
// {chunking x TLP} matrix.
__global__ __launch_bounds__(256, 4) void qgen19(
        const float* __restrict__ x, const float* __restrict__ qp,
        float* __restrict__ out) {
    __shared__ __align__(16) f32x4 smem[4][512];   // 32 KB relay slabs
    __shared__ float lmMs[64 * DIM];               // 8 KB dedicated M

    const int t = threadIdx.x;
    const int wid = t >> 6, lane = t & 63;
    const int l15 = lane & 15, kg = lane >> 4;
    const float RV = 0.07957747154594767f; // 0.5/(2*pi): v_sin/v_cos take revolutions

    f32x4* relay = smem[wid];

    float base[DIM];
    half8 BhF[4], BlF[4];

    // ---- x loads -> registers (issue early; latency hides under the sim)
    float xv[NQ];
    auto load_x = [&](int c) {
        const float* xp = x + ((size_t)blockIdx.x * (256 * CHUNKS) + c * 256
                               + wid * 64 + lane) * NQ;
        #pragma unroll
        for (int w = 0; w < NQ; ++w) xv[w] = xp[w];
    };
    // trig + product state from xv (verified R1-R20)
    auto build_base = [&]() {
        float cn[NQ], sn[NQ];
        #pragma unroll
        for (int w = 0; w < NQ; ++w) {
            float h = xv[w] * RV;
            cn[w] = __builtin_amdgcn_cosf(h);
            sn[w] = __builtin_amdgcn_sinf(h);
        }
        base[0] = cn[0]; base[1] = sn[0];
        #pragma unroll
        for (int w = 1; w < NQ; ++w) {
            #pragma unroll
            for (int j = (1 << w) - 1; j >= 0; --j) {
                float v = base[j];
                base[2*j + 1] = v * sn[w];
                base[2*j]     = v * cn[w];
            }
        }
    };
    // relay base -> B-frag order (wave-private slab; same-wave in-order DS)
    auto build_bfrags = [&]() {
        #pragma unroll
        for (int q = 0; q < 8; ++q)
            relay[q * 64 + lane] = *(f32x4*)&base[q * 4];
        #pragma unroll
        for (int tb = 0; tb < 4; ++tb) {
            f32x4 r0 = relay[(kg*2 + 0) * 64 + tb*16 + l15];
            f32x4 r1 = relay[(kg*2 + 1) * 64 + tb*16 + l15];
            float b8[8] = {r0[0], r0[1], r0[2], r0[3], r1[0], r1[1], r1[2], r1[3]};
            half8 h, lo;
            #pragma unroll
            for (int e = 0; e < 8; ++e) {
                _Float16 hh = (_Float16)b8[e];
                h[e]  = hh;
                lo[e] = (_Float16)(b8[e] - (float)hh);
            }
            BhF[tb] = h; BlF[tb] = lo;
        }
    };

    load_x(0);   // x in flight during the sim

    // ---- distributed ADJOINT sim (verified R19/R20): g = wid,
    // row rl = lane>>2, sub = lane&3, elements i = sub*8+e.
    {
        const int g  = wid;
        const int rl = lane >> 2, sub = lane & 3;
        float st[8], sgn[8];
        #pragma unroll
        for (int e = 0; e < 8; ++e) {
            st[e]  = (sub*8 + e == rl) ? 1.0f : 0.0f;
            sgn[e] = flip_par(sub*8 + e) ? -1.0f : 1.0f;
        }
        #pragma unroll
        for (int l = NL - 1; l >= 0; --l) {
            #pragma unroll
            for (int w = 0; w < NQ; ++w) {
                float h = qp[g*(NL*NQ) + l*NQ + w] * RV;
                float c = __builtin_amdgcn_cosf(h);
                float s = __builtin_amdgcn_sinf(h);
                if (w == 0) {            // bit4 = sub>>1, partner lane^2
                    float ss = (sub & 2) ? -s : s;
                    #pragma unroll
                    for (int e = 0; e < 8; ++e) {
                        float p = __shfl_xor(st[e], 2, 64);
                        st[e] = c*st[e] + ss*p;
                    }
                } else if (w == 1) {     // bit3 = sub&1, partner lane^1
                    float ss = (sub & 1) ? -s : s;
                    #pragma unroll
                    for (int e = 0; e < 8; ++e) {
                        float p = __shfl_xor(st[e], 1, 64);
                        st[e] = c*st[e] + ss*p;
                    }
                } else {                 // intra-lane: str = 1<<(4-w) in {4,2,1}
                    const int str = 1 << (4 - w);
                    #pragma unroll
                    for (int e = 0; e < 8; ++e) {
                        if (!(e & str)) {
                            float a0 = st[e], a1 = st[e + str];
                            st[e]       = c*a0 + s*a1;   // adjoint RY
                            st[e + str] = c*a1 - s*a0;
                        }
                    }
                }
            }
            if (l != 0) {
                #pragma unroll
                for (int e = 0; e < 8; ++e) st[e] *= sgn[e];
            }
        }
        const int row = g * PATCH + rl;
        #pragma unroll
        for (int e = 0; e < 8; ++e)
            lmMs[(row << 5) + ((sub*8 + e + row) & 31)] = st[e];
    }

    build_base();     // trig/base (xv arrived during sim)
    build_bfrags();
    __syncthreads();  // lmMs ready; balanced arrival (all waves equal work)

    // ---- A-fragments from lmMs (b32 reads, 2-way max), f16 hi/lo split
    half8 MhA[NG], MlA[NG];
    #pragma unroll
    for (int g = 0; g < NG; ++g) {
        const int row = g * PATCH + l15;
        float m8[8];
        #pragma unroll
        for (int e = 0; e < 8; ++e)
            m8[e] = lmMs[(row << 5) + ((kg*8 + e + row) & 31)];
        half8 h, lo;
        #pragma unroll
        for (int e = 0; e < 8; ++e) {
            _Float16 hh = (_Float16)m8[e];
            h[e]  = hh;
            lo[e] = (_Float16)(m8[e] - (float)hh);
        }
        MhA[g] = h; MlA[g] = lo;
    }

    // ---- main, FULLY UNROLLED (rule #20). Per tb: 4 g x 3 MFMA ->
    // DIRECT dwordx4 stores (4 per lane per tb, one 256-B row, back-to-back
    // -> L2 merges to full lines; verified R20).
    {
        float* ob = out + ((size_t)blockIdx.x * (256 * CHUNKS) + wid * 64) * 64;
        #pragma unroll
        for (int tb = 0; tb < 4; ++tb) {
            #pragma unroll
            for (int g = 0; g < NG; ++g) {
                f32x4 acc = {0.f, 0.f, 0.f, 0.f};
                acc = __builtin_amdgcn_mfma_f32_16x16x32_f16(MhA[g], BhF[tb], acc, 0, 0, 0);
                acc = __builtin_amdgcn_mfma_f32_16x16x32_f16(MlA[g], BhF[tb], acc, 0, 0, 0);
                acc = __builtin_amdgcn_mfma_f32_16x16x32_f16(MhA[g], BlF[tb], acc, 0, 0, 0);
                // D layout (m89-verified): reg r = slot kg*4+r, col l15 = batch.
                float p0 = acc[0]*acc[0], p1 = acc[1]*acc[1];
                float p2 = acc[2]*acc[2], p3 = acc[3]*acc[3];
                float mx = fmaxf(fmaxf(p0, p1), fmaxf(p2, p3));
                mx = fmaxf(mx, __shfl_xor(mx, 16, 64));   // combine the 4 kg lanes
                mx = fmaxf(mx, __shfl_xor(mx, 32, 64));
                float inv = __builtin_amdgcn_rcpf(mx);
                f32x4 v = {p0*inv, p1*inv, p2*inv, p3*inv};
                // direct: batch (tb*16+l15) row, slot quad g*16+kg*4
                *(f32x4*)&ob[(tb*16 + l15)*64 + g*16 + kg*4] = v;
            }
        }
    }
}

extern "C" void kernel_launch(void* const* d_in, const int* in_sizes, int n_in,
                              void* d_out, int out_size, void* d_ws, size_t ws_size,
                              hipStream_t stream) {
    const float* x  = (const float*)d_in[0];
    const float* qp = (const float*)d_in[1];
    float* out = (float*)d_out;
    const int B = in_sizes[0] / NQ;          // 262144
    qgen19<<<B / (256 * CHUNKS), 256, 0, stream>>>(x, qp, out);
}